// Round 3
// baseline (303.797 us; speedup 1.0000x reference)
//
#include <hip/hip_runtime.h>
#include <hip/hip_bf16.h>

#define BATCH 256
#define NODE 256
#define FDIM 64
#define DIM 64
#define TK 20
#define BN 65536

typedef const float* fpc;

// ---------------- K1: top-20 cosine graph + emb attention scalars ----------------
__global__ void k_graph(fpc emb, fpc att_em_i, fpc att_em_j,
                        int* __restrict__ topk, float* __restrict__ emi, float* __restrict__ emj){
  __shared__ float s_cos[NODE];
  __shared__ float s_wi[DIM];
  const int i = blockIdx.x;
  const int t = threadIdx.x;
  if (t < DIM) s_wi[t] = emb[i*DIM + t];
  __syncthreads();
  // thread t computes cos(i, t)
  float dot = 0.f, nj = 0.f, ni = 0.f;
  for (int f = 0; f < DIM; ++f){
    float wj = emb[t*DIM + f];
    float wi = s_wi[f];
    dot = fmaf(wi, wj, dot);
    nj  = fmaf(wj, wj, nj);
    ni  = fmaf(wi, wi, ni);
  }
  s_cos[t] = dot / (sqrtf(ni) * sqrtf(nj));
  __syncthreads();

  if (t < 64){
    // wave 0: 20 rounds of argmax (tie -> lower index) over 256 values
    float v0 = s_cos[t], v1 = s_cos[t+64], v2 = s_cos[t+128], v3 = s_cos[t+192];
    int taken = 0;
    for (int r = 0; r < TK; ++r){
      float bv = (taken & 1) ? -3.f : v0; int bi = t;
      float c;
      c = (taken & 2) ? -3.f : v1; if (c > bv){ bv = c; bi = t+64;  }
      c = (taken & 4) ? -3.f : v2; if (c > bv){ bv = c; bi = t+128; }
      c = (taken & 8) ? -3.f : v3; if (c > bv){ bv = c; bi = t+192; }
      for (int m = 1; m < 64; m <<= 1){
        float ov = __shfl_xor(bv, m, 64);
        int   oi = __shfl_xor(bi, m, 64);
        if (ov > bv || (ov == bv && oi < bi)){ bv = ov; bi = oi; }
      }
      if (t == 0) topk[i*TK + r] = bi;
      if ((bi & 63) == t) taken |= 1 << (bi >> 6);
    }
  } else if (t < 128){
    int d = t - 64;
    float w = s_wi[d];
    float p1 = w * att_em_i[d];
    float p2 = w * att_em_j[d];
    for (int m = 1; m < 64; m <<= 1){
      p1 += __shfl_xor(p1, m, 64);
      p2 += __shfl_xor(p2, m, 64);
    }
    if (d == 0){ emi[i] = p1; emj[i] = p2; }
  }
}

// ---------------- K2 (fused): per-batch xl GEMM (LDS) + edge softmax + aggregation + bn1 stats ----------------
// One block per batch b. xl lives only in LDS (bf16). agg written to global; bn1 sums atomically.
__global__ void __launch_bounds__(256) k_fused(fpc data, fpc lin_w, fpc att_i, fpc att_j,
                        const int* __restrict__ topk,
                        const float* __restrict__ emi_g, const float* __restrict__ emj_g,
                        fpc gnn_bias, float* __restrict__ agg,
                        float* __restrict__ bn1s, float* __restrict__ bn1q){
  __shared__ float s_lw[FDIM][DIM];            // 16 KB
  __shared__ __hip_bfloat16 s_xl[NODE*DIM];    // 32 KB
  __shared__ float s_x[4][FDIM];               // 1 KB
  __shared__ float s_ai[NODE], s_aj[NODE];     // 2 KB
  __shared__ float s_emi[NODE], s_emj[NODE];   // 2 KB
  __shared__ float s_alpha[4][24];
  __shared__ int   s_src[4][24];
  __shared__ float s_ps[4][64], s_pq[4][64];   // 2 KB

  const int t = threadIdx.x, w = t >> 6, lane = t & 63;
  const int b = blockIdx.x;

  #pragma unroll
  for (int i = 0; i < 16; ++i){
    int idx = t + i*256;                       // 0..4095
    s_lw[idx >> 6][idx & 63] = lin_w[idx];
  }
  s_emi[t] = emi_g[t];
  s_emj[t] = emj_g[t];
  __syncthreads();

  const float ati = att_i[lane];
  const float atj = att_j[lane];

  // phase 1: xl = data[b] @ lin_w  (wave w owns rows w*64 .. w*64+63)
  for (int j = 0; j < 64; ++j){
    const int r = w*64 + j;
    s_x[w][lane] = data[(b*NODE + r)*FDIM + lane];
    float a0 = 0.f, a1 = 0.f, a2 = 0.f, a3 = 0.f;
    #pragma unroll
    for (int f = 0; f < 64; f += 4){
      a0 = fmaf(s_x[w][f+0], s_lw[f+0][lane], a0);
      a1 = fmaf(s_x[w][f+1], s_lw[f+1][lane], a1);
      a2 = fmaf(s_x[w][f+2], s_lw[f+2][lane], a2);
      a3 = fmaf(s_x[w][f+3], s_lw[f+3][lane], a3);
    }
    float acc = (a0 + a1) + (a2 + a3);
    s_xl[r*DIM + lane] = __float2bfloat16(acc);
    float p1 = acc * ati;
    float p2 = acc * atj;
    for (int m = 1; m < 64; m <<= 1){
      p1 += __shfl_xor(p1, m, 64);
      p2 += __shfl_xor(p2, m, 64);
    }
    if (lane == 0){ s_ai[r] = p1; s_aj[r] = p2; }
  }
  __syncthreads();

  const float bias = gnn_bias[lane];
  float sum = 0.f, sq = 0.f;

  // phase 2: per-node softmax over 21 incoming edges + weighted aggregation
  for (int j = 0; j < 64; ++j){
    const int i = w*64 + j;                    // dst node
    float lg = -1e30f;
    int sl = 0;
    if (lane < 21){
      sl = (lane < 20) ? topk[i*TK + lane] : i;
      bool valid = (lane == 20) || (sl != i);  // remove_self_loops on topk edges, keep appended loop
      if (valid){
        float l = s_ai[i] + s_emi[i] + s_aj[sl] + s_emj[sl];
        lg = (l >= 0.f) ? l : 0.2f*l;          // leaky_relu(0.2)
      }
    }
    float m = lg;
    for (int s = 1; s < 64; s <<= 1) m = fmaxf(m, __shfl_xor(m, s, 64));
    float e = (lg > -1e29f) ? __expf(lg - m) : 0.f;
    float den = e;
    for (int s = 1; s < 64; s <<= 1) den += __shfl_xor(den, s, 64);
    if (lane < 21){ s_alpha[w][lane] = e / den; s_src[w][lane] = sl; }
    // same-wave LDS write->read: LDS pipe is in-order per wave
    float acc = bias;
    #pragma unroll
    for (int k = 0; k < 21; ++k)
      acc = fmaf(s_alpha[w][k], __bfloat162float(s_xl[s_src[w][k]*DIM + lane]), acc);
    agg[(b*NODE + i)*DIM + lane] = acc;
    sum += acc; sq = fmaf(acc, acc, sq);
  }
  s_ps[w][lane] = sum; s_pq[w][lane] = sq;
  __syncthreads();
  if (t < 64){
    atomicAdd(&bn1s[t], s_ps[0][t] + s_ps[1][t] + s_ps[2][t] + s_ps[3][t]);
    atomicAdd(&bn1q[t], s_pq[0][t] + s_pq[1][t] + s_pq[2][t] + s_pq[3][t]);
  }
}

// ---------------- K4: bn1 finalize + ReLU (in place) + bn2 partial stats on y ----------------
__global__ void __launch_bounds__(256) k_bn1_apply(float* __restrict__ agg, fpc emb, fpc g1, fpc be1,
                          const float* __restrict__ bn1s, const float* __restrict__ bn1q,
                          float* __restrict__ bn2s, float* __restrict__ bn2q){
  const int t = threadIdx.x, w = t >> 6, lane = t & 63;
  const float mean = bn1s[lane] * (1.f/BN);
  const float var  = bn1q[lane] * (1.f/BN) - mean*mean;
  const float sc   = g1[lane] * rsqrtf(var + 1e-5f);
  const float sh   = be1[lane] - mean*sc;
  const int rbase = blockIdx.x*64 + w*16;
  float ys = 0.f, yq = 0.f;
  for (int j = 0; j < 16; ++j){
    int r = rbase + j;
    float x = agg[r*DIM + lane];
    float g = fmaxf(fmaf(x, sc, sh), 0.f);
    agg[r*DIM + lane] = g;                       // gnn_out in place
    float y = g * emb[(r & 255)*DIM + lane];
    ys += y; yq = fmaf(y, y, yq);
  }
  __shared__ float ps[4][64], pq[4][64];
  ps[w][lane] = ys; pq[w][lane] = yq;
  __syncthreads();
  if (t < 64){
    float S = ps[0][t] + ps[1][t] + ps[2][t] + ps[3][t];
    float Q = pq[0][t] + pq[1][t] + pq[2][t] + pq[3][t];
    atomicAdd(&bn2s[t], S);
    atomicAdd(&bn2q[t], Q);
  }
}

// ---------------- K5: encoded[b][c] += gnn[b, kchunk] @ enc_w[kchunk, c] (split-K) ----------------
__global__ void __launch_bounds__(256) k_enc(const float* __restrict__ gnn, fpc enc_w,
                                             float* __restrict__ encoded){
  __shared__ float g[16][1024];                  // 64 KB
  const int t = threadIdx.x;
  const int kt = blockIdx.x, bt = blockIdx.y;
  const int kbase = kt*1024;
  for (int bl = 0; bl < 16; ++bl){
    #pragma unroll
    for (int i = 0; i < 4; ++i){
      int idx = t + i*256;
      g[bl][idx] = gnn[(bt*16 + bl)*16384 + kbase + idx];
    }
  }
  __syncthreads();
  const int w = t >> 6, c = t & 63;
  const int bl0 = w*4;
  float a0 = 0.f, a1 = 0.f, a2 = 0.f, a3 = 0.f;
  for (int k = 0; k < 1024; k += 4){
    float e0 = enc_w[(kbase + k + 0)*64 + c];
    float e1 = enc_w[(kbase + k + 1)*64 + c];
    float e2 = enc_w[(kbase + k + 2)*64 + c];
    float e3 = enc_w[(kbase + k + 3)*64 + c];
    float4 q0 = *(const float4*)&g[bl0 + 0][k];
    float4 q1 = *(const float4*)&g[bl0 + 1][k];
    float4 q2 = *(const float4*)&g[bl0 + 2][k];
    float4 q3 = *(const float4*)&g[bl0 + 3][k];
    a0 = fmaf(q0.x, e0, fmaf(q0.y, e1, fmaf(q0.z, e2, fmaf(q0.w, e3, a0))));
    a1 = fmaf(q1.x, e0, fmaf(q1.y, e1, fmaf(q1.z, e2, fmaf(q1.w, e3, a1))));
    a2 = fmaf(q2.x, e0, fmaf(q2.y, e1, fmaf(q2.z, e2, fmaf(q2.w, e3, a2))));
    a3 = fmaf(q3.x, e0, fmaf(q3.y, e1, fmaf(q3.z, e2, fmaf(q3.w, e3, a3))));
  }
  atomicAdd(&encoded[(bt*16 + bl0 + 0)*64 + c], a0);
  atomicAdd(&encoded[(bt*16 + bl0 + 1)*64 + c], a1);
  atomicAdd(&encoded[(bt*16 + bl0 + 2)*64 + c], a2);
  atomicAdd(&encoded[(bt*16 + bl0 + 3)*64 + c], a3);
}

// ---------------- K6: arrangement = (encoded + enc_b) @ arr_w + arr_b ----------------
__global__ void k_arr(const float* __restrict__ encoded, fpc enc_b, fpc arr_w, fpc arr_b,
                      float* __restrict__ out){
  const int b = threadIdx.x;                     // 0..255
  float o[7];
  #pragma unroll
  for (int j = 0; j < 7; ++j) o[j] = arr_b[j];
  for (int c = 0; c < 64; ++c){
    float e = encoded[b*64 + c] + enc_b[c];
    #pragma unroll
    for (int j = 0; j < 7; ++j) o[j] = fmaf(e, arr_w[c*7 + j], o[j]);
  }
  #pragma unroll
  for (int j = 0; j < 7; ++j) out[65536 + b*7 + j] = o[j];
}

// ---------------- K7: score = bn2(relu) head ----------------
__global__ void __launch_bounds__(256) k_score(const float* __restrict__ gnn, fpc emb, fpc g2, fpc be2,
                      const float* __restrict__ bn2s, const float* __restrict__ bn2q,
                      fpc out_w, fpc out_b, float* __restrict__ out){
  const int t = threadIdx.x, w = t >> 6, lane = t & 63;
  const float mean = bn2s[lane] * (1.f/BN);
  const float var  = bn2q[lane] * (1.f/BN) - mean*mean;
  const float sc   = g2[lane] * rsqrtf(var + 1e-5f);
  const float sh   = be2[lane] - mean*sc;
  const float ow   = out_w[lane];
  const float ob   = out_b[0];
  const int rbase = blockIdx.x*64 + w*16;
  for (int j = 0; j < 16; ++j){
    int r = rbase + j;
    float y  = gnn[r*DIM + lane] * emb[(r & 255)*DIM + lane];
    float yh = fmaxf(fmaf(y, sc, sh), 0.f);
    float p  = yh * ow;
    for (int m = 1; m < 64; m <<= 1) p += __shfl_xor(p, m, 64);
    if (lane == 0) out[r] = p + ob;
  }
}

extern "C" void kernel_launch(void* const* d_in, const int* in_sizes, int n_in,
                              void* d_out, int out_size, void* d_ws, size_t ws_size,
                              hipStream_t stream) {
  fpc data     = (fpc)d_in[0];
  fpc emb      = (fpc)d_in[1];
  fpc lin_w    = (fpc)d_in[2];
  fpc att_i    = (fpc)d_in[3];
  fpc att_j    = (fpc)d_in[4];
  fpc att_em_i = (fpc)d_in[5];
  fpc att_em_j = (fpc)d_in[6];
  fpc gnn_bias = (fpc)d_in[7];
  fpc g1       = (fpc)d_in[8];
  fpc be1      = (fpc)d_in[9];
  fpc g2       = (fpc)d_in[10];
  fpc be2      = (fpc)d_in[11];
  fpc enc_w    = (fpc)d_in[12];
  fpc enc_b    = (fpc)d_in[13];
  fpc arr_w    = (fpc)d_in[14];
  fpc arr_b    = (fpc)d_in[15];
  fpc out_w    = (fpc)d_in[16];
  fpc out_b    = (fpc)d_in[17];

  // workspace layout (floats) -- total 4,216,576 floats = 16.09 MB
  float* fw = (float*)d_ws;
  int* topk      = (int*)d_ws;          // [0, 5120) ints
  float* emi     = fw + 5120;           // 256
  float* emj     = fw + 5376;           // 256
  float* bn1s    = fw + 5632;           // 64  -- zeroed region start
  float* bn1q    = fw + 5696;           // 64
  float* bn2s    = fw + 5760;           // 64
  float* bn2q    = fw + 5824;           // 64
  float* encoded = fw + 5888;           // 16384 -- zeroed region end (22272)
  float* agg     = fw + 22272;          // 65536*64 f32 (becomes gnn_out in place)
  float* out     = (float*)d_out;

  hipMemsetAsync((void*)bn1s, 0, 16640u*sizeof(float), stream);

  k_graph    <<<256,  256, 0, stream>>>(emb, att_em_i, att_em_j, topk, emi, emj);
  k_fused    <<<256,  256, 0, stream>>>(data, lin_w, att_i, att_j, topk, emi, emj,
                                        gnn_bias, agg, bn1s, bn1q);
  k_bn1_apply<<<1024, 256, 0, stream>>>(agg, emb, g1, be1, bn1s, bn1q, bn2s, bn2q);
  k_enc      <<<dim3(16,16), 256, 0, stream>>>(agg, enc_w, encoded);
  k_arr      <<<1,    256, 0, stream>>>(encoded, enc_b, arr_w, arr_b, out);
  k_score    <<<1024, 256, 0, stream>>>(agg, emb, g2, be2, bn2s, bn2q, out_w, out_b, out);
}

// Round 4
// 285.968 us; speedup vs baseline: 1.0623x; 1.0623x over previous
//
#include <hip/hip_runtime.h>
#include <hip/hip_bf16.h>

#define BATCH 256
#define NODE 256
#define FDIM 64
#define DIM 64
#define TK 20
#define BN 65536

typedef const float* fpc;

// ---------------- K1: top-20 cosine graph + emb attention scalars ----------------
__global__ void k_graph(fpc emb, fpc att_em_i, fpc att_em_j,
                        int* __restrict__ topk, float* __restrict__ emi, float* __restrict__ emj){
  __shared__ float s_cos[NODE];
  __shared__ float s_wi[DIM];
  const int i = blockIdx.x;
  const int t = threadIdx.x;
  if (t < DIM) s_wi[t] = emb[i*DIM + t];
  __syncthreads();
  float dot = 0.f, nj = 0.f, ni = 0.f;
  for (int f = 0; f < DIM; ++f){
    float wj = emb[t*DIM + f];
    float wi = s_wi[f];
    dot = fmaf(wi, wj, dot);
    nj  = fmaf(wj, wj, nj);
    ni  = fmaf(wi, wi, ni);
  }
  s_cos[t] = dot / (sqrtf(ni) * sqrtf(nj));
  __syncthreads();

  if (t < 64){
    // wave 0: 20 rounds of argmax (tie -> lower index) over 256 values
    float v0 = s_cos[t], v1 = s_cos[t+64], v2 = s_cos[t+128], v3 = s_cos[t+192];
    int taken = 0;
    for (int r = 0; r < TK; ++r){
      float bv = (taken & 1) ? -3.f : v0; int bi = t;
      float c;
      c = (taken & 2) ? -3.f : v1; if (c > bv){ bv = c; bi = t+64;  }
      c = (taken & 4) ? -3.f : v2; if (c > bv){ bv = c; bi = t+128; }
      c = (taken & 8) ? -3.f : v3; if (c > bv){ bv = c; bi = t+192; }
      for (int m = 1; m < 64; m <<= 1){
        float ov = __shfl_xor(bv, m, 64);
        int   oi = __shfl_xor(bi, m, 64);
        if (ov > bv || (ov == bv && oi < bi)){ bv = ov; bi = oi; }
      }
      if (t == 0) topk[i*TK + r] = bi;
      if ((bi & 63) == t) taken |= 1 << (bi >> 6);
    }
  } else if (t < 128){
    int d = t - 64;
    float w = s_wi[d];
    float p1 = w * att_em_i[d];
    float p2 = w * att_em_j[d];
    for (int m = 1; m < 64; m <<= 1){
      p1 += __shfl_xor(p1, m, 64);
      p2 += __shfl_xor(p2, m, 64);
    }
    if (d == 0){ emi[i] = p1; emj[i] = p2; }
  }
}

// ---------------- K2: xl = x @ lin_w (bf16 out) + aip/ajp scalars ----------------
// lin_w column held in 64 VGPRs/lane; data rows read as wave-broadcast float4 (no LDS).
__global__ void __launch_bounds__(256) k_xl(fpc data, fpc lin_w, fpc att_i, fpc att_j,
                     fpc emi, fpc emj,
                     __hip_bfloat16* __restrict__ xl,
                     float* __restrict__ aip, float* __restrict__ ajp){
  const int t = threadIdx.x, w = t >> 6, lane = t & 63;
  float lw[64];
  #pragma unroll
  for (int f = 0; f < 64; ++f) lw[f] = lin_w[f*64 + lane];
  const float ati = att_i[lane], atj = att_j[lane];
  const int R0 = blockIdx.x*32 + w*8;        // 2048 blocks x 32 rows; wave: 8 rows
  for (int g = 0; g < 2; ++g){
    const int rb = R0 + g*4;
    float acc[4];
    #pragma unroll
    for (int j = 0; j < 4; ++j){
      const float4* xp = (const float4*)(data + (size_t)(rb + j)*64);
      float a0 = 0.f, a1 = 0.f, a2 = 0.f, a3 = 0.f;
      #pragma unroll
      for (int f4 = 0; f4 < 16; ++f4){
        float4 xq = xp[f4];                  // wave-uniform address -> broadcast
        a0 = fmaf(xq.x, lw[f4*4+0], a0);
        a1 = fmaf(xq.y, lw[f4*4+1], a1);
        a2 = fmaf(xq.z, lw[f4*4+2], a2);
        a3 = fmaf(xq.w, lw[f4*4+3], a3);
      }
      acc[j] = (a0 + a1) + (a2 + a3);
    }
    #pragma unroll
    for (int j = 0; j < 4; ++j){
      const int r = rb + j;
      xl[(size_t)r*64 + lane] = __float2bfloat16(acc[j]);
      float p1 = acc[j]*ati, p2 = acc[j]*atj;
      #pragma unroll
      for (int m = 1; m < 64; m <<= 1){
        p1 += __shfl_xor(p1, m, 64);
        p2 += __shfl_xor(p2, m, 64);
      }
      if (lane == 0){
        const int node = r & 255;
        aip[r] = p1 + emi[node];             // ai + att_em_i-dot, pre-added
        ajp[r] = p2 + emj[node];
      }
    }
  }
}

// ---------------- K3: wave-per-node edge softmax + bf16 gather aggregation ----------------
__global__ void __launch_bounds__(256) k_attn_agg(const int* __restrict__ topk,
                         const __hip_bfloat16* __restrict__ xl,
                         fpc aip, fpc ajp, fpc gnn_bias, float* __restrict__ agg){
  __shared__ float s_alpha[4][32];
  __shared__ int   s_src[4][32];
  const int t = threadIdx.x, w = t >> 6, lane = t & 63;
  const int v = blockIdx.x*4 + w;            // dst node in [0, BN)
  const int i = v & 255, b = v >> 8;
  float lg = -1e30f; int sl = 0;
  if (lane < 21){
    sl = (lane < 20) ? topk[i*TK + lane] : i;
    if (lane == 20 || sl != i){              // remove_self_loops, keep appended loop
      float l = aip[v] + ajp[b*NODE + sl];
      lg = (l >= 0.f) ? l : 0.2f*l;          // leaky_relu(0.2)
    }
  }
  float m = lg;
  for (int s = 1; s < 64; s <<= 1) m = fmaxf(m, __shfl_xor(m, s, 64));
  float e = (lg > -1e29f) ? __expf(lg - m) : 0.f;
  float den = e;
  for (int s = 1; s < 64; s <<= 1) den += __shfl_xor(den, s, 64);
  if (lane < 21){ s_alpha[w][lane] = e / den; s_src[w][lane] = b*NODE + sl; }
  // same-wave LDS RAW: in-order (verified round 3)
  float acc = gnn_bias[lane];
  #pragma unroll
  for (int k = 0; k < 21; ++k)
    acc = fmaf(s_alpha[w][k], __bfloat162float(xl[(size_t)s_src[w][k]*64 + lane]), acc);
  agg[(size_t)v*64 + lane] = acc;
}

// ---------------- K3b: per-channel sum / sumsq over [BN, 64] ----------------
__global__ void __launch_bounds__(256) k_stats(const float* __restrict__ src,
                                               float* __restrict__ sums, float* __restrict__ sqs){
  const int t = threadIdx.x, w = t >> 6, lane = t & 63;
  const int rbase = blockIdx.x*64 + w*16;
  float s = 0.f, q = 0.f;
  #pragma unroll 4
  for (int j = 0; j < 16; ++j){
    float x = src[(size_t)(rbase + j)*64 + lane];
    s += x; q = fmaf(x, x, q);
  }
  __shared__ float ps[4][64], pq[4][64];
  ps[w][lane] = s; pq[w][lane] = q;
  __syncthreads();
  if (t < 64){
    atomicAdd(&sums[t], ps[0][t] + ps[1][t] + ps[2][t] + ps[3][t]);
    atomicAdd(&sqs[t],  pq[0][t] + pq[1][t] + pq[2][t] + pq[3][t]);
  }
}

// ---------------- K4: bn1 finalize + ReLU (in place) + bn2 partial stats ----------------
__global__ void __launch_bounds__(256) k_bn1_apply(float* __restrict__ agg, fpc emb, fpc g1, fpc be1,
                          const float* __restrict__ bn1s, const float* __restrict__ bn1q,
                          float* __restrict__ bn2s, float* __restrict__ bn2q){
  const int t = threadIdx.x, w = t >> 6, lane = t & 63;
  const float mean = bn1s[lane] * (1.f/BN);
  const float var  = bn1q[lane] * (1.f/BN) - mean*mean;
  const float sc   = g1[lane] * rsqrtf(var + 1e-5f);
  const float sh   = be1[lane] - mean*sc;
  const int rbase = blockIdx.x*64 + w*16;
  float ys = 0.f, yq = 0.f;
  #pragma unroll 4
  for (int j = 0; j < 16; ++j){
    const int r = rbase + j;
    float x = agg[(size_t)r*64 + lane];
    float g = fmaxf(fmaf(x, sc, sh), 0.f);
    agg[(size_t)r*64 + lane] = g;            // gnn_out in place
    float y = g * emb[(r & 255)*64 + lane];
    ys += y; yq = fmaf(y, y, yq);
  }
  __shared__ float ps[4][64], pq[4][64];
  ps[w][lane] = ys; pq[w][lane] = yq;
  __syncthreads();
  if (t < 64){
    atomicAdd(&bn2s[t], ps[0][t] + ps[1][t] + ps[2][t] + ps[3][t]);
    atomicAdd(&bn2q[t], pq[0][t] + pq[1][t] + pq[2][t] + pq[3][t]);
  }
}

// ---------------- K5: split-K encoder GEMM, grid (64 kt, 16 bt) ----------------
__global__ void __launch_bounds__(256) k_enc(const float* __restrict__ gnn, fpc enc_w,
                                             float* __restrict__ encoded){
  __shared__ float s_g[16][256];             // 16 KB
  const int t = threadIdx.x;
  const int kt = blockIdx.x, bt = blockIdx.y;
  const int kbase = kt*256;
  #pragma unroll
  for (int i = 0; i < 16; ++i){
    int idx = t + i*256, row = idx >> 8, k = idx & 255;
    s_g[row][k] = gnn[(size_t)(bt*16 + row)*16384 + kbase + k];
  }
  __syncthreads();
  const int w = t >> 6, c = t & 63, r0 = w*4;
  float a[4] = {0.f, 0.f, 0.f, 0.f};
  for (int k = 0; k < 256; k += 4){
    float e0 = enc_w[(size_t)(kbase + k + 0)*64 + c];
    float e1 = enc_w[(size_t)(kbase + k + 1)*64 + c];
    float e2 = enc_w[(size_t)(kbase + k + 2)*64 + c];
    float e3 = enc_w[(size_t)(kbase + k + 3)*64 + c];
    #pragma unroll
    for (int r = 0; r < 4; ++r){
      float4 gq = *(const float4*)&s_g[r0 + r][k];
      a[r] = fmaf(gq.x, e0, fmaf(gq.y, e1, fmaf(gq.z, e2, fmaf(gq.w, e3, a[r]))));
    }
  }
  #pragma unroll
  for (int r = 0; r < 4; ++r)
    atomicAdd(&encoded[(bt*16 + r0 + r)*64 + c], a[r]);
}

// ---------------- K6: score head (float4, 4 rows/wave, width-16 reduce) + arr in block 0 ----------------
__global__ void __launch_bounds__(256) k_score(const float* __restrict__ gnn, fpc emb, fpc g2, fpc be2,
                      const float* __restrict__ bn2s, const float* __restrict__ bn2q,
                      fpc out_w, fpc out_b,
                      const float* __restrict__ encoded, fpc enc_b, fpc arr_w, fpc arr_b,
                      float* __restrict__ out){
  const int t = threadIdx.x, w = t >> 6, lane = t & 63;
  const int qc = lane & 15, rq = lane >> 4;
  float sc[4], sh[4], ow[4];
  #pragma unroll
  for (int k = 0; k < 4; ++k){
    const int d = qc*4 + k;
    float mean = bn2s[d] * (1.f/BN);
    float var  = bn2q[d] * (1.f/BN) - mean*mean;
    sc[k] = g2[d] * rsqrtf(var + 1e-5f);
    sh[k] = be2[d] - mean*sc[k];
    ow[k] = out_w[d];
  }
  const float ob = out_b[0];
  const float4* gnn4 = (const float4*)gnn;
  const float4* emb4 = (const float4*)emb;
  const int base = blockIdx.x*64 + w*16;
  #pragma unroll
  for (int it = 0; it < 4; ++it){
    const int r = base + it*4 + rq;
    float4 y4 = gnn4[(size_t)r*16 + qc];
    float4 e4 = emb4[(r & 255)*16 + qc];
    float p = 0.f, yh;
    yh = fmaxf(fmaf(y4.x*e4.x, sc[0], sh[0]), 0.f); p = fmaf(yh, ow[0], p);
    yh = fmaxf(fmaf(y4.y*e4.y, sc[1], sh[1]), 0.f); p = fmaf(yh, ow[1], p);
    yh = fmaxf(fmaf(y4.z*e4.z, sc[2], sh[2]), 0.f); p = fmaf(yh, ow[2], p);
    yh = fmaxf(fmaf(y4.w*e4.w, sc[3], sh[3]), 0.f); p = fmaf(yh, ow[3], p);
    #pragma unroll
    for (int m = 1; m < 16; m <<= 1) p += __shfl_xor(p, m, 16);
    if (qc == 0) out[r] = p + ob;
  }
  // arrangement head: block 0, thread = batch row
  if (blockIdx.x == 0){
    const int b = t;
    float o[7];
    #pragma unroll
    for (int j = 0; j < 7; ++j) o[j] = arr_b[j];
    for (int c = 0; c < 64; ++c){
      float e = encoded[b*64 + c] + enc_b[c];
      #pragma unroll
      for (int j = 0; j < 7; ++j) o[j] = fmaf(e, arr_w[c*7 + j], o[j]);
    }
    #pragma unroll
    for (int j = 0; j < 7; ++j) out[65536 + b*7 + j] = o[j];
  }
}

extern "C" void kernel_launch(void* const* d_in, const int* in_sizes, int n_in,
                              void* d_out, int out_size, void* d_ws, size_t ws_size,
                              hipStream_t stream) {
  fpc data     = (fpc)d_in[0];
  fpc emb      = (fpc)d_in[1];
  fpc lin_w    = (fpc)d_in[2];
  fpc att_i    = (fpc)d_in[3];
  fpc att_j    = (fpc)d_in[4];
  fpc att_em_i = (fpc)d_in[5];
  fpc att_em_j = (fpc)d_in[6];
  fpc gnn_bias = (fpc)d_in[7];
  fpc g1       = (fpc)d_in[8];
  fpc be1      = (fpc)d_in[9];
  fpc g2       = (fpc)d_in[10];
  fpc be2      = (fpc)d_in[11];
  fpc enc_w    = (fpc)d_in[12];
  fpc enc_b    = (fpc)d_in[13];
  fpc arr_w    = (fpc)d_in[14];
  fpc arr_b    = (fpc)d_in[15];
  fpc out_w    = (fpc)d_in[16];
  fpc out_b    = (fpc)d_in[17];

  // workspace layout (float offsets) -- total ~24.6 MB
  float* fw = (float*)d_ws;
  int*   topk    = (int*)d_ws;            // [0, 5120) ints
  float* emi     = fw + 5120;             // 256
  float* emj     = fw + 5376;             // 256
  float* bn1s    = fw + 5632;             // 64   -- zeroed region start
  float* bn1q    = fw + 5696;             // 64
  float* bn2s    = fw + 5760;             // 64
  float* bn2q    = fw + 5824;             // 64
  float* encoded = fw + 5888;             // 16384 -- zeroed region end (22272)
  float* aip     = fw + 22272;            // 65536
  float* ajp     = fw + 87808;            // 65536
  float* agg     = fw + 153344;           // 65536*64 f32 (becomes gnn_out in place)
  __hip_bfloat16* xl = (__hip_bfloat16*)(fw + 4347648);  // 65536*64 bf16 = 8.4 MB
  float* out     = (float*)d_out;

  hipMemsetAsync((void*)bn1s, 0, 16640u*sizeof(float), stream);

  k_graph    <<<256,   256, 0, stream>>>(emb, att_em_i, att_em_j, topk, emi, emj);
  k_xl       <<<2048,  256, 0, stream>>>(data, lin_w, att_i, att_j, emi, emj, xl, aip, ajp);
  k_attn_agg <<<16384, 256, 0, stream>>>(topk, xl, aip, ajp, gnn_bias, agg);
  k_stats    <<<1024,  256, 0, stream>>>(agg, bn1s, bn1q);
  k_bn1_apply<<<1024,  256, 0, stream>>>(agg, emb, g1, be1, bn1s, bn1q, bn2s, bn2q);
  k_enc      <<<dim3(64,16), 256, 0, stream>>>(agg, enc_w, encoded);
  k_score    <<<1024,  256, 0, stream>>>(agg, emb, g2, be2, bn2s, bn2q, out_w, out_b,
                                         encoded, enc_b, arr_w, arr_b, out);
}

// Round 5
// 266.367 us; speedup vs baseline: 1.1405x; 1.0736x over previous
//
#include <hip/hip_runtime.h>
#include <hip/hip_bf16.h>

#define BATCH 256
#define NODE 256
#define FDIM 64
#define DIM 64
#define TK 20
#define BN 65536

typedef const float* fpc;

// ---------------- K1: top-20 cosine graph + emb scalars + u_i/u_j precompute ----------------
__global__ void k_graph(fpc emb, fpc att_em_i, fpc att_em_j, fpc lin_w, fpc att_i, fpc att_j,
                        int* __restrict__ topk, float* __restrict__ emi, float* __restrict__ emj,
                        float* __restrict__ u_i, float* __restrict__ u_j){
  const int t = threadIdx.x;
  if (blockIdx.x == 256){
    // u_i = lin_w @ att_i ; u_j = lin_w @ att_j   (64 floats each)
    if (t < 64){
      float s = 0.f;
      for (int c = 0; c < 64; ++c) s = fmaf(lin_w[t*64 + c], att_i[c], s);
      u_i[t] = s;
    } else if (t < 128){
      const int f = t - 64;
      float s = 0.f;
      for (int c = 0; c < 64; ++c) s = fmaf(lin_w[f*64 + c], att_j[c], s);
      u_j[f] = s;
    }
    return;
  }
  __shared__ float s_cos[NODE];
  __shared__ float s_wi[DIM];
  const int i = blockIdx.x;
  if (t < DIM) s_wi[t] = emb[i*DIM + t];
  __syncthreads();
  float dot = 0.f, nj = 0.f, ni = 0.f;
  for (int f = 0; f < DIM; ++f){
    float wj = emb[t*DIM + f];
    float wi = s_wi[f];
    dot = fmaf(wi, wj, dot);
    nj  = fmaf(wj, wj, nj);
    ni  = fmaf(wi, wi, ni);
  }
  s_cos[t] = dot / (sqrtf(ni) * sqrtf(nj));
  __syncthreads();

  if (t < 64){
    // wave 0: 20 rounds of argmax (tie -> lower index) over 256 values
    float v0 = s_cos[t], v1 = s_cos[t+64], v2 = s_cos[t+128], v3 = s_cos[t+192];
    int taken = 0;
    for (int r = 0; r < TK; ++r){
      float bv = (taken & 1) ? -3.f : v0; int bi = t;
      float c;
      c = (taken & 2) ? -3.f : v1; if (c > bv){ bv = c; bi = t+64;  }
      c = (taken & 4) ? -3.f : v2; if (c > bv){ bv = c; bi = t+128; }
      c = (taken & 8) ? -3.f : v3; if (c > bv){ bv = c; bi = t+192; }
      for (int m = 1; m < 64; m <<= 1){
        float ov = __shfl_xor(bv, m, 64);
        int   oi = __shfl_xor(bi, m, 64);
        if (ov > bv || (ov == bv && oi < bi)){ bv = ov; bi = oi; }
      }
      if (t == 0) topk[i*TK + r] = bi;
      if ((bi & 63) == t) taken |= 1 << (bi >> 6);
    }
  } else if (t < 128){
    int d = t - 64;
    float w = s_wi[d];
    float p1 = w * att_em_i[d];
    float p2 = w * att_em_j[d];
    for (int m = 1; m < 64; m <<= 1){
      p1 += __shfl_xor(p1, m, 64);
      p2 += __shfl_xor(p2, m, 64);
    }
    if (d == 0){ emi[i] = p1; emj[i] = p2; }
  }
}

// ---------------- K2: xl = x @ lin_w (bf16 out) -- no cross-lane ops ----------------
__global__ void __launch_bounds__(256) k_xl(fpc data, fpc lin_w, __hip_bfloat16* __restrict__ xl){
  const int t = threadIdx.x, w = t >> 6, lane = t & 63;
  float lw[64];
  #pragma unroll
  for (int f = 0; f < 64; ++f) lw[f] = lin_w[f*64 + lane];
  const int R0 = blockIdx.x*32 + w*8;        // 2048 blocks x 32 rows; 8 rows/wave
  #pragma unroll
  for (int g = 0; g < 2; ++g){
    const int rb = R0 + g*4;
    float acc[4];
    #pragma unroll
    for (int j = 0; j < 4; ++j){
      const float4* xp = (const float4*)(data + (size_t)(rb + j)*64);
      float a0 = 0.f, a1 = 0.f, a2 = 0.f, a3 = 0.f;
      #pragma unroll
      for (int f4 = 0; f4 < 16; ++f4){
        float4 xq = xp[f4];                  // wave-uniform address -> one transaction
        a0 = fmaf(xq.x, lw[f4*4+0], a0);
        a1 = fmaf(xq.y, lw[f4*4+1], a1);
        a2 = fmaf(xq.z, lw[f4*4+2], a2);
        a3 = fmaf(xq.w, lw[f4*4+3], a3);
      }
      acc[j] = (a0 + a1) + (a2 + a3);
    }
    #pragma unroll
    for (int j = 0; j < 4; ++j)
      xl[(size_t)(rb + j)*64 + lane] = __float2bfloat16(acc[j]);
  }
}

// ---------------- K2b: aip/ajp = data . u_{i,j} + em_{i,j}  (thread-per-row, no reductions) ----------------
__global__ void __launch_bounds__(256) k_scal(fpc data, const float* __restrict__ u_i,
                       const float* __restrict__ u_j, fpc emi, fpc emj,
                       float* __restrict__ aip, float* __restrict__ ajp){
  __shared__ float4 s_ui[16], s_uj[16];
  const int t = threadIdx.x;
  if (t < 16)      s_ui[t]      = ((const float4*)u_i)[t];
  else if (t < 32) s_uj[t - 16] = ((const float4*)u_j)[t - 16];
  __syncthreads();
  const int r = blockIdx.x*256 + t;
  const float4* d4 = (const float4*)data + (size_t)r*16;
  float p1 = 0.f, p2 = 0.f;
  #pragma unroll
  for (int f4 = 0; f4 < 16; ++f4){
    float4 d = d4[f4];
    float4 ui = s_ui[f4], uj = s_uj[f4];
    p1 = fmaf(d.x, ui.x, fmaf(d.y, ui.y, fmaf(d.z, ui.z, fmaf(d.w, ui.w, p1))));
    p2 = fmaf(d.x, uj.x, fmaf(d.y, uj.y, fmaf(d.z, uj.z, fmaf(d.w, uj.w, p2))));
  }
  aip[r] = p1 + emi[r & 255];
  ajp[r] = p2 + emj[r & 255];
}

// ---------------- K3: wave-per-node edge softmax + bf16 gather aggregation ----------------
__global__ void __launch_bounds__(256) k_attn_agg(const int* __restrict__ topk,
                         const __hip_bfloat16* __restrict__ xl,
                         fpc aip, fpc ajp, fpc gnn_bias, float* __restrict__ agg){
  __shared__ float s_alpha[4][32];
  __shared__ int   s_src[4][32];
  const int t = threadIdx.x, w = t >> 6, lane = t & 63;
  const int v = blockIdx.x*4 + w;            // dst node in [0, BN)
  const int i = v & 255, b = v >> 8;
  float lg = -1e30f; int sl = 0;
  if (lane < 21){
    sl = (lane < 20) ? topk[i*TK + lane] : i;
    if (lane == 20 || sl != i){              // remove_self_loops, keep appended loop
      float l = aip[v] + ajp[b*NODE + sl];
      lg = (l >= 0.f) ? l : 0.2f*l;          // leaky_relu(0.2)
    }
  }
  float m = lg;
  for (int s = 1; s < 64; s <<= 1) m = fmaxf(m, __shfl_xor(m, s, 64));
  float e = (lg > -1e29f) ? __expf(lg - m) : 0.f;
  float den = e;
  for (int s = 1; s < 64; s <<= 1) den += __shfl_xor(den, s, 64);
  if (lane < 21){ s_alpha[w][lane] = e / den; s_src[w][lane] = b*NODE + sl; }
  // same-wave LDS RAW: in-order per wave
  float acc = gnn_bias[lane];
  #pragma unroll
  for (int k = 0; k < 21; ++k)
    acc = fmaf(s_alpha[w][k], __bfloat162float(xl[(size_t)s_src[w][k]*64 + lane]), acc);
  agg[(size_t)v*64 + lane] = acc;
}

// ---------------- K3b: per-channel sum / sumsq over [BN, 64] ----------------
__global__ void __launch_bounds__(256) k_stats(const float* __restrict__ src,
                                               float* __restrict__ sums, float* __restrict__ sqs){
  const int t = threadIdx.x, w = t >> 6, lane = t & 63;
  const int rbase = blockIdx.x*64 + w*16;
  float s = 0.f, q = 0.f;
  #pragma unroll 4
  for (int j = 0; j < 16; ++j){
    float x = src[(size_t)(rbase + j)*64 + lane];
    s += x; q = fmaf(x, x, q);
  }
  __shared__ float ps[4][64], pq[4][64];
  ps[w][lane] = s; pq[w][lane] = q;
  __syncthreads();
  if (t < 64){
    atomicAdd(&sums[t], ps[0][t] + ps[1][t] + ps[2][t] + ps[3][t]);
    atomicAdd(&sqs[t],  pq[0][t] + pq[1][t] + pq[2][t] + pq[3][t]);
  }
}

// ---------------- K4: bn1 finalize + ReLU (in place) + bn2 partial stats ----------------
__global__ void __launch_bounds__(256) k_bn1_apply(float* __restrict__ agg, fpc emb, fpc g1, fpc be1,
                          const float* __restrict__ bn1s, const float* __restrict__ bn1q,
                          float* __restrict__ bn2s, float* __restrict__ bn2q){
  const int t = threadIdx.x, w = t >> 6, lane = t & 63;
  const float mean = bn1s[lane] * (1.f/BN);
  const float var  = bn1q[lane] * (1.f/BN) - mean*mean;
  const float sc   = g1[lane] * rsqrtf(var + 1e-5f);
  const float sh   = be1[lane] - mean*sc;
  const int rbase = blockIdx.x*64 + w*16;
  float ys = 0.f, yq = 0.f;
  #pragma unroll 4
  for (int j = 0; j < 16; ++j){
    const int r = rbase + j;
    float x = agg[(size_t)r*64 + lane];
    float g = fmaxf(fmaf(x, sc, sh), 0.f);
    agg[(size_t)r*64 + lane] = g;            // gnn_out in place
    float y = g * emb[(r & 255)*64 + lane];
    ys += y; yq = fmaf(y, y, yq);
  }
  __shared__ float ps[4][64], pq[4][64];
  ps[w][lane] = ys; pq[w][lane] = yq;
  __syncthreads();
  if (t < 64){
    atomicAdd(&bn2s[t], ps[0][t] + ps[1][t] + ps[2][t] + ps[3][t]);
    atomicAdd(&bn2q[t], pq[0][t] + pq[1][t] + pq[2][t] + pq[3][t]);
  }
}

// ---------------- K5: split-K encoder GEMM -> partials (no atomics), grid (64 kt, 16 bt) ----------------
__global__ void __launch_bounds__(256) k_enc(const float* __restrict__ gnn, fpc enc_w,
                                             float* __restrict__ part){
  __shared__ float s_g[16][256];             // 16 KB
  const int t = threadIdx.x;
  const int kt = blockIdx.x, bt = blockIdx.y;
  const int kbase = kt*256;
  #pragma unroll
  for (int i = 0; i < 16; ++i){
    int idx = t + i*256, row = idx >> 8, k = idx & 255;
    s_g[row][k] = gnn[(size_t)(bt*16 + row)*16384 + kbase + k];
  }
  __syncthreads();
  const int w = t >> 6, c = t & 63, r0 = w*4;
  float a[4] = {0.f, 0.f, 0.f, 0.f};
  for (int k = 0; k < 256; k += 4){
    float e0 = enc_w[(size_t)(kbase + k + 0)*64 + c];
    float e1 = enc_w[(size_t)(kbase + k + 1)*64 + c];
    float e2 = enc_w[(size_t)(kbase + k + 2)*64 + c];
    float e3 = enc_w[(size_t)(kbase + k + 3)*64 + c];
    #pragma unroll
    for (int r = 0; r < 4; ++r){
      float4 gq = *(const float4*)&s_g[r0 + r][k];
      a[r] = fmaf(gq.x, e0, fmaf(gq.y, e1, fmaf(gq.z, e2, fmaf(gq.w, e3, a[r]))));
    }
  }
  #pragma unroll
  for (int r = 0; r < 4; ++r)
    part[(size_t)kt*16384 + (bt*16 + r0 + r)*64 + c] = a[r];
}

// ---------------- K5b: reduce split-K partials -> encoded ----------------
__global__ void __launch_bounds__(256) k_red(const float* __restrict__ part,
                                             float* __restrict__ encoded){
  const int idx = blockIdx.x*256 + threadIdx.x;   // 64 blocks x 256 = 16384
  float s = 0.f;
  #pragma unroll 8
  for (int kt = 0; kt < 64; ++kt) s += part[(size_t)kt*16384 + idx];
  encoded[idx] = s;
}

// ---------------- K6: score head (float4, 4 rows/wave, width-16 reduce) + arr in block 0 ----------------
__global__ void __launch_bounds__(256) k_score(const float* __restrict__ gnn, fpc emb, fpc g2, fpc be2,
                      const float* __restrict__ bn2s, const float* __restrict__ bn2q,
                      fpc out_w, fpc out_b,
                      const float* __restrict__ encoded, fpc enc_b, fpc arr_w, fpc arr_b,
                      float* __restrict__ out){
  const int t = threadIdx.x, w = t >> 6, lane = t & 63;
  const int qc = lane & 15, rq = lane >> 4;
  float sc[4], sh[4], ow[4];
  #pragma unroll
  for (int k = 0; k < 4; ++k){
    const int d = qc*4 + k;
    float mean = bn2s[d] * (1.f/BN);
    float var  = bn2q[d] * (1.f/BN) - mean*mean;
    sc[k] = g2[d] * rsqrtf(var + 1e-5f);
    sh[k] = be2[d] - mean*sc[k];
    ow[k] = out_w[d];
  }
  const float ob = out_b[0];
  const float4* gnn4 = (const float4*)gnn;
  const float4* emb4 = (const float4*)emb;
  const int base = blockIdx.x*64 + w*16;
  #pragma unroll
  for (int it = 0; it < 4; ++it){
    const int r = base + it*4 + rq;
    float4 y4 = gnn4[(size_t)r*16 + qc];
    float4 e4 = emb4[(r & 255)*16 + qc];
    float p = 0.f, yh;
    yh = fmaxf(fmaf(y4.x*e4.x, sc[0], sh[0]), 0.f); p = fmaf(yh, ow[0], p);
    yh = fmaxf(fmaf(y4.y*e4.y, sc[1], sh[1]), 0.f); p = fmaf(yh, ow[1], p);
    yh = fmaxf(fmaf(y4.z*e4.z, sc[2], sh[2]), 0.f); p = fmaf(yh, ow[2], p);
    yh = fmaxf(fmaf(y4.w*e4.w, sc[3], sh[3]), 0.f); p = fmaf(yh, ow[3], p);
    #pragma unroll
    for (int m = 1; m < 16; m <<= 1) p += __shfl_xor(p, m, 16);
    if (qc == 0) out[r] = p + ob;
  }
  // arrangement head: block 0, thread = batch row
  if (blockIdx.x == 0){
    const int b = t;
    float o[7];
    #pragma unroll
    for (int j = 0; j < 7; ++j) o[j] = arr_b[j];
    for (int c = 0; c < 64; ++c){
      float e = encoded[b*64 + c] + enc_b[c];
      #pragma unroll
      for (int j = 0; j < 7; ++j) o[j] = fmaf(e, arr_w[c*7 + j], o[j]);
    }
    #pragma unroll
    for (int j = 0; j < 7; ++j) out[65536 + b*7 + j] = o[j];
  }
}

extern "C" void kernel_launch(void* const* d_in, const int* in_sizes, int n_in,
                              void* d_out, int out_size, void* d_ws, size_t ws_size,
                              hipStream_t stream) {
  fpc data     = (fpc)d_in[0];
  fpc emb      = (fpc)d_in[1];
  fpc lin_w    = (fpc)d_in[2];
  fpc att_i    = (fpc)d_in[3];
  fpc att_j    = (fpc)d_in[4];
  fpc att_em_i = (fpc)d_in[5];
  fpc att_em_j = (fpc)d_in[6];
  fpc gnn_bias = (fpc)d_in[7];
  fpc g1       = (fpc)d_in[8];
  fpc be1      = (fpc)d_in[9];
  fpc g2       = (fpc)d_in[10];
  fpc be2      = (fpc)d_in[11];
  fpc enc_w    = (fpc)d_in[12];
  fpc enc_b    = (fpc)d_in[13];
  fpc arr_w    = (fpc)d_in[14];
  fpc arr_b    = (fpc)d_in[15];
  fpc out_w    = (fpc)d_in[16];
  fpc out_b    = (fpc)d_in[17];

  // workspace layout (float offsets) -- total 24.6 MB (same footprint that passed round 4)
  float* fw = (float*)d_ws;
  int*   topk    = (int*)d_ws;            // [0, 5120) ints
  float* emi     = fw + 5120;             // 256
  float* emj     = fw + 5376;             // 256
  float* u_i     = fw + 5632;             // 64
  float* u_j     = fw + 5696;             // 64
  float* bn1s    = fw + 5760;             // 64  -- zero region start
  float* bn1q    = fw + 5824;             // 64
  float* bn2s    = fw + 5888;             // 64
  float* bn2q    = fw + 5952;             // 64  -- zero region end (6016)
  float* encoded = fw + 6016;             // 16384 (fully written by k_red)
  float* aip     = fw + 22400;            // 65536
  float* ajp     = fw + 87936;            // 65536
  float* agg     = fw + 153472;           // 65536*64 f32 (becomes gnn_out in place)
  __hip_bfloat16* xl = (__hip_bfloat16*)(fw + 4347776);  // 65536*64 bf16 = 8.4 MB
  float* part    = (float*)xl;            // 64*16384 f32 = 4 MB, reuses dead xl region
  float* out     = (float*)d_out;

  hipMemsetAsync((void*)bn1s, 0, 256u*sizeof(float), stream);

  k_graph    <<<257,   256, 0, stream>>>(emb, att_em_i, att_em_j, lin_w, att_i, att_j,
                                         topk, emi, emj, u_i, u_j);
  k_xl       <<<2048,  256, 0, stream>>>(data, lin_w, xl);
  k_scal     <<<256,   256, 0, stream>>>(data, u_i, u_j, emi, emj, aip, ajp);
  k_attn_agg <<<16384, 256, 0, stream>>>(topk, xl, aip, ajp, gnn_bias, agg);
  k_stats    <<<1024,  256, 0, stream>>>(agg, bn1s, bn1q);
  k_bn1_apply<<<1024,  256, 0, stream>>>(agg, emb, g1, be1, bn1s, bn1q, bn2s, bn2q);
  k_enc      <<<dim3(64,16), 256, 0, stream>>>(agg, enc_w, part);
  k_red      <<<64,    256, 0, stream>>>(part, encoded);
  k_score    <<<1024,  256, 0, stream>>>(agg, emb, g2, be2, bn2s, bn2q, out_w, out_b,
                                         encoded, enc_b, arr_w, arr_b, out);
}